// Round 4
// baseline (123.015 us; speedup 1.0000x reference)
//
#include <hip/hip_runtime.h>

typedef _Float16 half8 __attribute__((ext_vector_type(8)));
typedef float floatx4 __attribute__((ext_vector_type(4)));
typedef unsigned int uint2v __attribute__((ext_vector_type(2)));

#define NSPLIT 64
#define KS 64
#define DIM 2048
#define NROW 128            // 2*KS rows of T per split
#define BK 128              // k-panel width
#define KSPL 8              // k-chunks per split (one block each) -> 512 blocks, 2/CU
#define KCH (DIM / KSPL)    // 256
#define NKC_A (KCH / BK)    // 2 panels per block
#define SST 152             // stage row stride (fp16): 304 B, 16B-aligned, 2-way banks (free)
#define GSZ (NROW * NROW)   // 16384 floats per partial-gram slab
#define GT_OFF (NSPLIT * KSPL * GSZ)  // ws offset of per-split sum-of-gram scalars

// pack two f32 -> one u32 fp16 pair (rtz)
__device__ __forceinline__ unsigned int pk16(float a, float b) {
  return __builtin_bit_cast(unsigned int, __builtin_amdgcn_cvt_pkrtz(a, b));
}

__global__ void init_kernel(float* out, float* ws) {
  if (threadIdx.x < 6) out[threadIdx.x] = 0.0f;        // incl. out[1]=0 for atomicMax
  if (threadIdx.x < NSPLIT) ws[GT_OFF + threadIdx.x] = 0.0f;
}

// ---- Kernel A: partial gram over one 256-wide k-chunk. grid = 512.
__global__ __launch_bounds__(1024) void gram_kernel(const float* __restrict__ src,
                                                    const float* __restrict__ tgt,
                                                    float* __restrict__ ws) {
  __shared__ __align__(16) _Float16 stage[NROW * SST];  // ~38 KB -> 2 blocks/CU
  __shared__ float red[16];

  const int p = blockIdx.x >> 3;
  const int c = blockIdx.x & (KSPL - 1);
  const int tid = threadIdx.x;
  const int lane = tid & 63;
  const int wave = tid >> 6;

  // staging: thread loads row srow, 4x float4 at panel cols c4 + {0,32,64,96}
  const int srow = tid >> 3;
  const int c4 = (tid & 7) * 4;
  const float* rowp = ((srow < KS) ? (src + (size_t)(p * KS + srow) * DIM)
                                   : (tgt + (size_t)(p * KS + (srow - KS)) * DIM)) +
                      c * KCH;

  // mfma: 16 waves in 4x4 grid; wave computes 32x32 (2x2 tiles of 16x16)
  const int wr = (wave >> 2) * 32;
  const int wc = (wave & 3) * 32;
  const int fr = lane & 15;
  const int fk = (lane >> 4) * 8;

  floatx4 acc00 = {0.f, 0.f, 0.f, 0.f};
  floatx4 acc01 = {0.f, 0.f, 0.f, 0.f};
  floatx4 acc10 = {0.f, 0.f, 0.f, 0.f};
  floatx4 acc11 = {0.f, 0.f, 0.f, 0.f};

  float4 f0, f1, f2, f3;
#define LOADK(kc)                                      \
  do {                                                 \
    const float* gp_ = rowp + (kc) * BK + c4;          \
    f0 = *(const float4*)(gp_);                        \
    f1 = *(const float4*)(gp_ + 32);                   \
    f2 = *(const float4*)(gp_ + 64);                   \
    f3 = *(const float4*)(gp_ + 96);                   \
  } while (0)

  LOADK(0);
  for (int kc = 0; kc < NKC_A; ++kc) {
    __syncthreads();
    {
      _Float16* sp = &stage[srow * SST + c4];
      *(uint2v*)(sp)      = (uint2v){pk16(f0.x, f0.y), pk16(f0.z, f0.w)};
      *(uint2v*)(sp + 32) = (uint2v){pk16(f1.x, f1.y), pk16(f1.z, f1.w)};
      *(uint2v*)(sp + 64) = (uint2v){pk16(f2.x, f2.y), pk16(f2.z, f2.w)};
      *(uint2v*)(sp + 96) = (uint2v){pk16(f3.x, f3.y), pk16(f3.z, f3.w)};
    }
    __syncthreads();
    if (kc + 1 < NKC_A) LOADK(kc + 1);  // prefetch hides under MFMA
#pragma unroll
    for (int ks = 0; ks < 4; ++ks) {
      const int ko = ks * 32 + fk;
      half8 a0 = *(const half8*)&stage[(wr + fr) * SST + ko];
      half8 a1 = *(const half8*)&stage[(wr + 16 + fr) * SST + ko];
      half8 b0 = *(const half8*)&stage[(wc + fr) * SST + ko];
      half8 b1 = *(const half8*)&stage[(wc + 16 + fr) * SST + ko];
      acc00 = __builtin_amdgcn_mfma_f32_16x16x32_f16(a0, b0, acc00, 0, 0, 0);
      acc01 = __builtin_amdgcn_mfma_f32_16x16x32_f16(a0, b1, acc01, 0, 0, 0);
      acc10 = __builtin_amdgcn_mfma_f32_16x16x32_f16(a1, b0, acc10, 0, 0, 0);
      acc11 = __builtin_amdgcn_mfma_f32_16x16x32_f16(a1, b1, acc11, 0, 0, 0);
    }
  }
#undef LOADK

  // store partial slab. C/D layout: col = lane&15, row = (lane>>4)*4 + reg
  float* wsp = ws + (size_t)blockIdx.x * GSZ;
  const int ccol = lane & 15;
  const int crow = (lane >> 4) * 4;
  float gsum = 0.0f;
#pragma unroll
  for (int r = 0; r < 4; ++r) {
    wsp[(wr + crow + r) * NROW + (wc + ccol)] = acc00[r];
    wsp[(wr + crow + r) * NROW + (wc + 16 + ccol)] = acc01[r];
    wsp[(wr + 16 + crow + r) * NROW + (wc + ccol)] = acc10[r];
    wsp[(wr + 16 + crow + r) * NROW + (wc + 16 + ccol)] = acc11[r];
    gsum += acc00[r] + acc01[r] + acc10[r] + acc11[r];
  }
  // block-reduce sum of this partial gram -> ws_gt[p]
#pragma unroll
  for (int m = 1; m <= 32; m <<= 1) gsum += __shfl_xor(gsum, m, 64);
  if (lane == 0) red[wave] = gsum;
  __syncthreads();
  if (tid == 0) {
    float t = 0.0f;
    for (int w = 0; w < 16; ++w) t += red[w];
    atomicAdd(&ws[GT_OFF + p], t);
  }
}

// ---- Kernel B: 4 blocks per split (32 rows each). grid = 256.
__global__ __launch_bounds__(1024) void reduce_kernel(const float* __restrict__ ws,
                                                      float* __restrict__ out) {
  __shared__ float sqv[NROW];
  __shared__ float bcast[8];
  __shared__ float redm[16];
  __shared__ float quad2[2];

  const int p = blockIdx.x >> 2;
  const int rb = blockIdx.x & 3;
  const int tid = threadIdx.x;
  const int lane = tid & 63;
  const int wave = tid >> 6;

  const int lr = tid >> 5;          // 0..31 local row
  const int cg = tid & 31;          // col group: cols 4*cg .. 4*cg+3
  const int row = rb * 32 + lr;

  // sum this thread's 4 gram entries across the 8 slabs (strip is L2/L3-hot)
  const float* base = ws + (size_t)(p * KSPL) * GSZ + row * NROW + cg * 4;
  float4 g = {0.f, 0.f, 0.f, 0.f};
#pragma unroll
  for (int c8 = 0; c8 < KSPL; ++c8) {
    float4 t = *(const float4*)(base + (size_t)c8 * GSZ);
    g.x += t.x; g.y += t.y; g.z += t.z; g.w += t.w;
  }

  // full diagonal (sq): same c8 order as strip sum -> exact l2_ii = 0
  if (tid < NROW) {
    const float* dp = ws + (size_t)(p * KSPL) * GSZ + tid * (NROW + 1);
    float d = 0.0f;
#pragma unroll
    for (int c8 = 0; c8 < KSPL; ++c8) d += dp[(size_t)c8 * GSZ];
    sqv[tid] = d;
  }
  if (tid < 2) quad2[tid] = 0.0f;
  __syncthreads();

  if (tid == 0) {
    float ssq = 0.0f;
    for (int i = 0; i < NROW; ++i) ssq += sqv[i];
    float gt = ws[GT_OFF + p];
    float suml2 = 2.0f * (float)NROW * ssq - 2.0f * gt;  // sum(l2) identity
    float bw = suml2 / (float)(NROW * NROW - NROW) * 0.25f;  // /(n^2-n) /KERNEL_MUL^2
    float mult = 1.0f;
    for (int k = 0; k < 5; ++k) {
      bcast[k] = 1.0f / (bw * mult + 1e-9f);
      mult *= 2.0f;
    }
  }
  __syncthreads();

  const float sqi = sqv[row];
  float l2r[4];
  float lmax = 0.0f;
#pragma unroll
  for (int k = 0; k < 4; ++k) {
    float v = sqi + sqv[cg * 4 + k] - 2.0f * ((const float*)&g)[k];
    l2r[k] = v;
    lmax = fmaxf(lmax, v);
  }

  if (p == NSPLIT - 1) {  // max l2 of last split
#pragma unroll
    for (int m = 1; m <= 32; m <<= 1) lmax = fmaxf(lmax, __shfl_xor(lmax, m, 64));
    if (lane == 0) redm[wave] = lmax;
    __syncthreads();
    if (tid == 0) {
      float mx = 0.0f;
      for (int w = 0; w < 16; ++w) mx = fmaxf(mx, redm[w]);
      atomicMax((int*)(out + 1), __float_as_int(mx));  // all values >= 0
    }
  }

  const float ib0 = bcast[0], ib1 = bcast[1], ib2 = bcast[2], ib3 = bcast[3], ib4 = bcast[4];
  float qsum = 0.0f;
#pragma unroll
  for (int k = 0; k < 4; ++k) {
    float v = l2r[k];
    qsum += __expf(-v * ib0) + __expf(-v * ib1) + __expf(-v * ib2) +
            __expf(-v * ib3) + __expf(-v * ib4);
  }
  // lanes 0-15,32-47: col-half X; 16-31,48-63: col-half Y.
  qsum += __shfl_xor(qsum, 1, 64);
  qsum += __shfl_xor(qsum, 2, 64);
  qsum += __shfl_xor(qsum, 4, 64);
  qsum += __shfl_xor(qsum, 8, 64);
  qsum += __shfl_xor(qsum, 32, 64);
  if (lane == 0) atomicAdd(&quad2[0], qsum);   // cols X
  if (lane == 16) atomicAdd(&quad2[1], qsum);  // cols Y
  __syncthreads();

  if (tid == 0) {
    const float inv = 1.0f / (4096.0f * 64.0f);  // /(64*64) then /P
    float qx = quad2[0], qy = quad2[1];
    if (rb < 2) {  // rows in X half: qx -> XX, qy -> XY
      atomicAdd(&out[0], (qx - qy) * inv);
      atomicAdd(&out[2], qx * inv);
      atomicAdd(&out[4], qy * inv);
    } else {       // rows in Y half: qy -> YY, qx -> YX
      atomicAdd(&out[0], (qy - qx) * inv);
      atomicAdd(&out[3], qy * inv);
      atomicAdd(&out[5], qx * inv);
    }
  }
}

extern "C" void kernel_launch(void* const* d_in, const int* in_sizes, int n_in,
                              void* d_out, int out_size, void* d_ws, size_t ws_size,
                              hipStream_t stream) {
  const float* src = (const float*)d_in[0];
  const float* tgt = (const float*)d_in[1];
  float* out = (float*)d_out;
  float* ws = (float*)d_ws;  // slabs 33.6 MB + 64 scalars
  init_kernel<<<1, 64, 0, stream>>>(out, ws);
  gram_kernel<<<NSPLIT * KSPL, 1024, 0, stream>>>(src, tgt, ws);
  reduce_kernel<<<NSPLIT * 4, 1024, 0, stream>>>(ws, out);
}

// Round 6
// 116.590 us; speedup vs baseline: 1.0551x; 1.0551x over previous
//
#include <hip/hip_runtime.h>

typedef _Float16 half8 __attribute__((ext_vector_type(8)));
typedef float floatx4 __attribute__((ext_vector_type(4)));
typedef unsigned int uint2v __attribute__((ext_vector_type(2)));

#define NSPLIT 64
#define KS 64
#define DIM 2048
#define NROW 128            // 2*KS rows of T per split
#define BK 128              // k-panel width
#define KSPL 4              // k-chunks per split -> 256 blocks, 1/CU
#define KCH (DIM / KSPL)    // 512
#define NKC_A (KCH / BK)    // 4 panels per block
#define SST 152             // stage row stride (fp16): 304 B, 16B-aligned, 2-way banks (free)
#define GSZ (NROW * NROW)   // 16384 floats per partial-gram slab
#define GT_OFF (NSPLIT * KSPL * GSZ)  // ws offset of per-split sum-of-gram scalars

// pack two f32 -> one u32 fp16 pair (rtz)
__device__ __forceinline__ unsigned int pk16(float a, float b) {
  return __builtin_bit_cast(unsigned int, __builtin_amdgcn_cvt_pkrtz(a, b));
}

__global__ void init_kernel(float* out, float* ws) {
  if (threadIdx.x < 6) out[threadIdx.x] = 0.0f;        // incl. out[1]=0 for atomicMax
  if (threadIdx.x < NSPLIT) ws[GT_OFF + threadIdx.x] = 0.0f;
}

// ---- Kernel A: partial gram over one 512-wide k-chunk. grid = 256 (1/CU).
// All 4 panels' global loads issued up-front: 256 KB/block streams continuously
// while convert+MFMA consume panels in order (vmcnt pipelining).
__global__ __launch_bounds__(1024, 4) void gram_kernel(const float* __restrict__ src,
                                                       const float* __restrict__ tgt,
                                                       float* __restrict__ ws) {
  __shared__ __align__(16) _Float16 stage[NROW * SST];  // ~38 KB
  __shared__ float red[16];

  const int p = blockIdx.x >> 2;
  const int c = blockIdx.x & (KSPL - 1);
  const int tid = threadIdx.x;
  const int lane = tid & 63;
  const int wave = tid >> 6;

  // staging: thread loads row srow, 4x float4 at panel cols c4 + {0,32,64,96}
  const int srow = tid >> 3;
  const int c4 = (tid & 7) * 4;
  const float* rowp = ((srow < KS) ? (src + (size_t)(p * KS + srow) * DIM)
                                   : (tgt + (size_t)(p * KS + (srow - KS)) * DIM)) +
                      c * KCH;

  // mfma: 16 waves in 4x4 grid; wave computes 32x32 (2x2 tiles of 16x16)
  const int wr = (wave >> 2) * 32;
  const int wc = (wave & 3) * 32;
  const int fr = lane & 15;
  const int fk = (lane >> 4) * 8;

  floatx4 acc00 = {0.f, 0.f, 0.f, 0.f};
  floatx4 acc01 = {0.f, 0.f, 0.f, 0.f};
  floatx4 acc10 = {0.f, 0.f, 0.f, 0.f};
  floatx4 acc11 = {0.f, 0.f, 0.f, 0.f};

  // ---- issue ALL panel loads now (64 VGPRs of payload, 16 loads in flight)
  float4 f[NKC_A][4];
#pragma unroll
  for (int kc = 0; kc < NKC_A; ++kc) {
    const float* gp = rowp + kc * BK + c4;
    f[kc][0] = *(const float4*)(gp);
    f[kc][1] = *(const float4*)(gp + 32);
    f[kc][2] = *(const float4*)(gp + 64);
    f[kc][3] = *(const float4*)(gp + 96);
  }

#pragma unroll
  for (int kc = 0; kc < NKC_A; ++kc) {
    __syncthreads();  // previous panel's LDS reads done before overwrite
    {
      _Float16* sp = &stage[srow * SST + c4];
      *(uint2v*)(sp)      = (uint2v){pk16(f[kc][0].x, f[kc][0].y), pk16(f[kc][0].z, f[kc][0].w)};
      *(uint2v*)(sp + 32) = (uint2v){pk16(f[kc][1].x, f[kc][1].y), pk16(f[kc][1].z, f[kc][1].w)};
      *(uint2v*)(sp + 64) = (uint2v){pk16(f[kc][2].x, f[kc][2].y), pk16(f[kc][2].z, f[kc][2].w)};
      *(uint2v*)(sp + 96) = (uint2v){pk16(f[kc][3].x, f[kc][3].y), pk16(f[kc][3].z, f[kc][3].w)};
    }
    __syncthreads();
#pragma unroll
    for (int ks = 0; ks < 4; ++ks) {
      const int ko = ks * 32 + fk;
      half8 a0 = *(const half8*)&stage[(wr + fr) * SST + ko];
      half8 a1 = *(const half8*)&stage[(wr + 16 + fr) * SST + ko];
      half8 b0 = *(const half8*)&stage[(wc + fr) * SST + ko];
      half8 b1 = *(const half8*)&stage[(wc + 16 + fr) * SST + ko];
      acc00 = __builtin_amdgcn_mfma_f32_16x16x32_f16(a0, b0, acc00, 0, 0, 0);
      acc01 = __builtin_amdgcn_mfma_f32_16x16x32_f16(a0, b1, acc01, 0, 0, 0);
      acc10 = __builtin_amdgcn_mfma_f32_16x16x32_f16(a1, b0, acc10, 0, 0, 0);
      acc11 = __builtin_amdgcn_mfma_f32_16x16x32_f16(a1, b1, acc11, 0, 0, 0);
    }
  }

  // store partial slab. C/D layout: col = lane&15, row = (lane>>4)*4 + reg
  float* wsp = ws + (size_t)blockIdx.x * GSZ;
  const int ccol = lane & 15;
  const int crow = (lane >> 4) * 4;
  float gsum = 0.0f;
#pragma unroll
  for (int r = 0; r < 4; ++r) {
    wsp[(wr + crow + r) * NROW + (wc + ccol)] = acc00[r];
    wsp[(wr + crow + r) * NROW + (wc + 16 + ccol)] = acc01[r];
    wsp[(wr + 16 + crow + r) * NROW + (wc + ccol)] = acc10[r];
    wsp[(wr + 16 + crow + r) * NROW + (wc + 16 + ccol)] = acc11[r];
    gsum += acc00[r] + acc01[r] + acc10[r] + acc11[r];
  }
  // block-reduce sum of this partial gram -> ws_gt[p]
#pragma unroll
  for (int m = 1; m <= 32; m <<= 1) gsum += __shfl_xor(gsum, m, 64);
  if (lane == 0) red[wave] = gsum;
  __syncthreads();
  if (tid == 0) {
    float t = 0.0f;
    for (int w = 0; w < 16; ++w) t += red[w];
    atomicAdd(&ws[GT_OFF + p], t);
  }
}

// ---- Kernel B: 4 blocks per split (32 rows each). grid = 256.
__global__ __launch_bounds__(1024) void reduce_kernel(const float* __restrict__ ws,
                                                      float* __restrict__ out) {
  __shared__ float sqv[NROW];
  __shared__ float bcast[8];
  __shared__ float redm[16];
  __shared__ float quad2[2];

  const int p = blockIdx.x >> 2;
  const int rb = blockIdx.x & 3;
  const int tid = threadIdx.x;
  const int lane = tid & 63;
  const int wave = tid >> 6;

  const int lr = tid >> 5;          // 0..31 local row
  const int cg = tid & 31;          // col group: cols 4*cg .. 4*cg+3
  const int row = rb * 32 + lr;

  // sum this thread's 4 gram entries across the slabs (strip is L2/L3-hot)
  const float* base = ws + (size_t)(p * KSPL) * GSZ + row * NROW + cg * 4;
  float4 g = {0.f, 0.f, 0.f, 0.f};
#pragma unroll
  for (int c8 = 0; c8 < KSPL; ++c8) {
    float4 t = *(const float4*)(base + (size_t)c8 * GSZ);
    g.x += t.x; g.y += t.y; g.z += t.z; g.w += t.w;
  }

  // full diagonal (sq): same c8 order as strip sum -> exact l2_ii = 0
  if (tid < NROW) {
    const float* dp = ws + (size_t)(p * KSPL) * GSZ + tid * (NROW + 1);
    float d = 0.0f;
#pragma unroll
    for (int c8 = 0; c8 < KSPL; ++c8) d += dp[(size_t)c8 * GSZ];
    sqv[tid] = d;
  }
  if (tid < 2) quad2[tid] = 0.0f;
  __syncthreads();

  if (tid == 0) {
    float ssq = 0.0f;
    for (int i = 0; i < NROW; ++i) ssq += sqv[i];
    float gt = ws[GT_OFF + p];
    float suml2 = 2.0f * (float)NROW * ssq - 2.0f * gt;  // sum(l2) identity
    float bw = suml2 / (float)(NROW * NROW - NROW) * 0.25f;  // /(n^2-n) /KERNEL_MUL^2
    float mult = 1.0f;
    for (int k = 0; k < 5; ++k) {
      bcast[k] = 1.0f / (bw * mult + 1e-9f);
      mult *= 2.0f;
    }
  }
  __syncthreads();

  const float sqi = sqv[row];
  float l2r[4];
  float lmax = 0.0f;
#pragma unroll
  for (int k = 0; k < 4; ++k) {
    float v = sqi + sqv[cg * 4 + k] - 2.0f * ((const float*)&g)[k];
    l2r[k] = v;
    lmax = fmaxf(lmax, v);
  }

  if (p == NSPLIT - 1) {  // max l2 of last split
#pragma unroll
    for (int m = 1; m <= 32; m <<= 1) lmax = fmaxf(lmax, __shfl_xor(lmax, m, 64));
    if (lane == 0) redm[wave] = lmax;
    __syncthreads();
    if (tid == 0) {
      float mx = 0.0f;
      for (int w = 0; w < 16; ++w) mx = fmaxf(mx, redm[w]);
      atomicMax((int*)(out + 1), __float_as_int(mx));  // all values >= 0
    }
  }

  const float ib0 = bcast[0], ib1 = bcast[1], ib2 = bcast[2], ib3 = bcast[3], ib4 = bcast[4];
  float qsum = 0.0f;
#pragma unroll
  for (int k = 0; k < 4; ++k) {
    float v = l2r[k];
    qsum += __expf(-v * ib0) + __expf(-v * ib1) + __expf(-v * ib2) +
            __expf(-v * ib3) + __expf(-v * ib4);
  }
  // lanes 0-15,32-47: col-half X; 16-31,48-63: col-half Y.
  qsum += __shfl_xor(qsum, 1, 64);
  qsum += __shfl_xor(qsum, 2, 64);
  qsum += __shfl_xor(qsum, 4, 64);
  qsum += __shfl_xor(qsum, 8, 64);
  qsum += __shfl_xor(qsum, 32, 64);
  if (lane == 0) atomicAdd(&quad2[0], qsum);   // cols X
  if (lane == 16) atomicAdd(&quad2[1], qsum);  // cols Y
  __syncthreads();

  if (tid == 0) {
    const float inv = 1.0f / (4096.0f * 64.0f);  // /(64*64) then /P
    float qx = quad2[0], qy = quad2[1];
    if (rb < 2) {  // rows in X half: qx -> XX, qy -> XY
      atomicAdd(&out[0], (qx - qy) * inv);
      atomicAdd(&out[2], qx * inv);
      atomicAdd(&out[4], qy * inv);
    } else {       // rows in Y half: qy -> YY, qx -> YX
      atomicAdd(&out[0], (qy - qx) * inv);
      atomicAdd(&out[3], qy * inv);
      atomicAdd(&out[5], qx * inv);
    }
  }
}

extern "C" void kernel_launch(void* const* d_in, const int* in_sizes, int n_in,
                              void* d_out, int out_size, void* d_ws, size_t ws_size,
                              hipStream_t stream) {
  const float* src = (const float*)d_in[0];
  const float* tgt = (const float*)d_in[1];
  float* out = (float*)d_out;
  float* ws = (float*)d_ws;  // slabs 16.8 MB + 64 scalars
  init_kernel<<<1, 64, 0, stream>>>(out, ws);
  gram_kernel<<<NSPLIT * KSPL, 1024, 0, stream>>>(src, tgt, ws);
  reduce_kernel<<<NSPLIT * 4, 1024, 0, stream>>>(ws, out);
}

// Round 7
// 109.462 us; speedup vs baseline: 1.1238x; 1.0651x over previous
//
#include <hip/hip_runtime.h>

typedef _Float16 half8 __attribute__((ext_vector_type(8)));
typedef float floatx4 __attribute__((ext_vector_type(4)));
typedef unsigned int uint2v __attribute__((ext_vector_type(2)));

#define NSPLIT 64
#define KS 64
#define DIM 2048
#define NROW 128            // 2*KS rows of T per split
#define BK 128              // k-panel width
#define KSPL 4              // k-chunks per split -> 256 blocks
#define KCH (DIM / KSPL)    // 512
#define NKC_A (KCH / BK)    // 4 panels per block
#define SST 152             // stage row stride (fp16): 304 B, 16B-aligned, 2-way banks (free)
#define GSZ (NROW * NROW)   // 16384 floats per partial-gram slab
#define NBLK (NSPLIT * KSPL)         // 256 gram/reduce blocks
#define GT2_OFF (NBLK * GSZ)         // per-gram-block sum-of-gram scalars (256)
#define PART_OFF (GT2_OFF + NBLK)    // per-reduce-block partials (256 x float4)

// Slab layout is MFMA-fragment-major: float index = wave*1024 + acc*256 + lane*4 + reg
// where wave = (row>>5)*4 + (col>>5); acc = ((row>>4)&1)*2 + ((col>>4)&1);
// lane = ((row&15)>>2)*16 + (col&15); reg = row&3.   (row,col) in [0,128)^2.

// pack two f32 -> one u32 fp16 pair (rtz)
__device__ __forceinline__ unsigned int pk16(float a, float b) {
  return __builtin_bit_cast(unsigned int, __builtin_amdgcn_cvt_pkrtz(a, b));
}

// ---- Kernel A: partial gram over one 512-wide k-chunk. grid = 256.
__global__ __launch_bounds__(1024) void gram_kernel(const float* __restrict__ src,
                                                    const float* __restrict__ tgt,
                                                    float* __restrict__ ws) {
  __shared__ __align__(16) _Float16 stage[NROW * SST];  // ~38 KB
  __shared__ float red[16];

  const int p = blockIdx.x >> 2;
  const int c = blockIdx.x & (KSPL - 1);
  const int tid = threadIdx.x;
  const int lane = tid & 63;
  const int wave = tid >> 6;

  // staging: thread loads row srow, 4x float4 at panel cols c4 + {0,32,64,96}
  const int srow = tid >> 3;
  const int c4 = (tid & 7) * 4;
  const float* rowp = ((srow < KS) ? (src + (size_t)(p * KS + srow) * DIM)
                                   : (tgt + (size_t)(p * KS + (srow - KS)) * DIM)) +
                      c * KCH;

  // mfma: 16 waves in 4x4 grid; wave computes 32x32 (2x2 tiles of 16x16)
  const int wr = (wave >> 2) * 32;
  const int wc = (wave & 3) * 32;
  const int fr = lane & 15;
  const int fk = (lane >> 4) * 8;

  floatx4 acc00 = {0.f, 0.f, 0.f, 0.f};
  floatx4 acc01 = {0.f, 0.f, 0.f, 0.f};
  floatx4 acc10 = {0.f, 0.f, 0.f, 0.f};
  floatx4 acc11 = {0.f, 0.f, 0.f, 0.f};

  float4 f0, f1, f2, f3;
#define LOADK(kc)                                      \
  do {                                                 \
    const float* gp_ = rowp + (kc) * BK + c4;          \
    f0 = *(const float4*)(gp_);                        \
    f1 = *(const float4*)(gp_ + 32);                   \
    f2 = *(const float4*)(gp_ + 64);                   \
    f3 = *(const float4*)(gp_ + 96);                   \
  } while (0)

  LOADK(0);
  for (int kc = 0; kc < NKC_A; ++kc) {
    __syncthreads();  // previous panel's LDS reads done before overwrite
    {
      _Float16* sp = &stage[srow * SST + c4];
      *(uint2v*)(sp)      = (uint2v){pk16(f0.x, f0.y), pk16(f0.z, f0.w)};
      *(uint2v*)(sp + 32) = (uint2v){pk16(f1.x, f1.y), pk16(f1.z, f1.w)};
      *(uint2v*)(sp + 64) = (uint2v){pk16(f2.x, f2.y), pk16(f2.z, f2.w)};
      *(uint2v*)(sp + 96) = (uint2v){pk16(f3.x, f3.y), pk16(f3.z, f3.w)};
    }
    __syncthreads();
    if (kc + 1 < NKC_A) LOADK(kc + 1);  // prefetch next panel under MFMA
#pragma unroll
    for (int ks = 0; ks < 4; ++ks) {
      const int ko = ks * 32 + fk;
      half8 a0 = *(const half8*)&stage[(wr + fr) * SST + ko];
      half8 a1 = *(const half8*)&stage[(wr + 16 + fr) * SST + ko];
      half8 b0 = *(const half8*)&stage[(wc + fr) * SST + ko];
      half8 b1 = *(const half8*)&stage[(wc + 16 + fr) * SST + ko];
      acc00 = __builtin_amdgcn_mfma_f32_16x16x32_f16(a0, b0, acc00, 0, 0, 0);
      acc01 = __builtin_amdgcn_mfma_f32_16x16x32_f16(a0, b1, acc01, 0, 0, 0);
      acc10 = __builtin_amdgcn_mfma_f32_16x16x32_f16(a1, b0, acc10, 0, 0, 0);
      acc11 = __builtin_amdgcn_mfma_f32_16x16x32_f16(a1, b1, acc11, 0, 0, 0);
    }
  }
#undef LOADK

  // fragment-major slab store: 4x contiguous 1KB/wave dwordx4 stores, no transpose
  float* wsp = ws + (size_t)blockIdx.x * GSZ + wave * 1024 + lane * 4;
  *(floatx4*)(wsp)       = acc00;
  *(floatx4*)(wsp + 256) = acc01;
  *(floatx4*)(wsp + 512) = acc10;
  *(floatx4*)(wsp + 768) = acc11;

  // block-reduce sum of this partial gram -> ws[GT2_OFF + blockIdx] (no atomics)
  float gsum = 0.0f;
#pragma unroll
  for (int r = 0; r < 4; ++r) gsum += acc00[r] + acc01[r] + acc10[r] + acc11[r];
#pragma unroll
  for (int m = 1; m <= 32; m <<= 1) gsum += __shfl_xor(gsum, m, 64);
  if (lane == 0) red[wave] = gsum;
  __syncthreads();
  if (tid == 0) {
    float t = 0.0f;
    for (int w = 0; w < 16; ++w) t += red[w];
    ws[GT2_OFF + blockIdx.x] = t;
  }
}

// ---- Kernel B: 4 blocks per split (32 rows each). grid = 256. No global atomics.
__global__ __launch_bounds__(1024) void reduce_kernel(const float* __restrict__ ws,
                                                      float* __restrict__ out) {
  __shared__ float sqv[NROW];
  __shared__ float bcast[8];
  __shared__ float redm[16];
  __shared__ float quad2[2];

  const int b = blockIdx.x;
  const int p = b >> 2;
  const int rb = b & 3;
  const int tid = threadIdx.x;
  const int lane = tid & 63;
  const int wave = tid >> 6;

  const int row = rb * 32 + (tid >> 5);
  const int cg = tid & 31;  // cols cg*4 .. cg*4+3

  const float* sb = ws + (size_t)(p * KSPL) * GSZ;
  // fragment-major index of (row, cg*4)
  const int wv = ((row >> 5) << 2) + (cg >> 3);
  const int a = (((row >> 4) & 1) << 1) + ((cg >> 2) & 1);
  const int ln = (((row & 15) >> 2) << 4) + ((cg & 3) << 2);
  const int idx = wv * 1024 + a * 256 + ln * 4 + (row & 3);

  float g0 = 0.f, g1 = 0.f, g2 = 0.f, g3 = 0.f;
#pragma unroll
  for (int c8 = 0; c8 < KSPL; ++c8) {
    const float* bp = sb + (size_t)c8 * GSZ + idx;
    g0 += bp[0]; g1 += bp[4]; g2 += bp[8]; g3 += bp[12];  // cols step lane by 1 -> +4 floats
  }

  // diagonal (sq): same slab order as strip -> exact l2_ii = 0
  if (tid < NROW) {
    const int i = tid;
    const int wd = (i >> 5) * 5;
    const int ad = ((i >> 4) & 1) * 3;
    const int lnd = (((i & 15) >> 2) << 4) + (i & 15);
    const int idxd = wd * 1024 + ad * 256 + lnd * 4 + (i & 3);
    float d = 0.0f;
#pragma unroll
    for (int c8 = 0; c8 < KSPL; ++c8) d += sb[(size_t)c8 * GSZ + idxd];
    sqv[i] = d;
  }
  if (tid < 2) quad2[tid] = 0.0f;
  __syncthreads();

  if (tid == 0) {
    float ssq = 0.0f;
    for (int i = 0; i < NROW; ++i) ssq += sqv[i];
    float gt = ws[GT2_OFF + p * 4 + 0] + ws[GT2_OFF + p * 4 + 1] +
               ws[GT2_OFF + p * 4 + 2] + ws[GT2_OFF + p * 4 + 3];
    float suml2 = 2.0f * (float)NROW * ssq - 2.0f * gt;  // sum(l2) identity
    float bw = suml2 / (float)(NROW * NROW - NROW) * 0.25f;  // /(n^2-n) /KERNEL_MUL^2
    float mult = 1.0f;
    for (int k = 0; k < 5; ++k) {
      bcast[k] = 1.0f / (bw * mult + 1e-9f);
      mult *= 2.0f;
    }
  }
  __syncthreads();

  const float sqi = sqv[row];
  float l2r[4];
  float lmax = 0.0f;
  {
    const float gg[4] = {g0, g1, g2, g3};
#pragma unroll
    for (int k = 0; k < 4; ++k) {
      float v = sqi + sqv[cg * 4 + k] - 2.0f * gg[k];
      l2r[k] = v;
      lmax = fmaxf(lmax, v);
    }
  }
#pragma unroll
  for (int m = 1; m <= 32; m <<= 1) lmax = fmaxf(lmax, __shfl_xor(lmax, m, 64));
  if (lane == 0) redm[wave] = lmax;

  const float ib0 = bcast[0], ib1 = bcast[1], ib2 = bcast[2], ib3 = bcast[3], ib4 = bcast[4];
  float qsum = 0.0f;
#pragma unroll
  for (int k = 0; k < 4; ++k) {
    float v = l2r[k];
    qsum += __expf(-v * ib0) + __expf(-v * ib1) + __expf(-v * ib2) +
            __expf(-v * ib3) + __expf(-v * ib4);
  }
  // lanes with bit4=0: col-half X; bit4=1: col-half Y
  qsum += __shfl_xor(qsum, 1, 64);
  qsum += __shfl_xor(qsum, 2, 64);
  qsum += __shfl_xor(qsum, 4, 64);
  qsum += __shfl_xor(qsum, 8, 64);
  qsum += __shfl_xor(qsum, 32, 64);
  if (lane == 0) atomicAdd(&quad2[0], qsum);   // LDS atomic, cols X
  if (lane == 16) atomicAdd(&quad2[1], qsum);  // LDS atomic, cols Y
  __syncthreads();

  if (tid == 0) {
    float mx = 0.0f;
    for (int w = 0; w < 16; ++w) mx = fmaxf(mx, redm[w]);
    float4* part = (float4*)(ws + PART_OFF);
    part[b] = make_float4(quad2[0], quad2[1], mx, 0.0f);
  }
}

// ---- Kernel C: combine 256 reduce-block partials, write all 6 outputs. grid = 1.
__global__ __launch_bounds__(256) void final_kernel(const float* __restrict__ ws,
                                                    float* __restrict__ out) {
  __shared__ float fr[4][5];
  const int tid = threadIdx.x;
  const int lane = tid & 63;
  const int wave = tid >> 6;
  const float4* part = (const float4*)(ws + PART_OFF);
  float4 pt = part[tid];
  const int rb = tid & 3;
  float xx = (rb < 2) ? pt.x : 0.0f;
  float xy = (rb < 2) ? pt.y : 0.0f;
  float yx = (rb >= 2) ? pt.x : 0.0f;
  float yy = (rb >= 2) ? pt.y : 0.0f;
  float mx = ((tid >> 2) == NSPLIT - 1) ? pt.z : 0.0f;
#pragma unroll
  for (int m = 1; m <= 32; m <<= 1) {
    xx += __shfl_xor(xx, m, 64);
    xy += __shfl_xor(xy, m, 64);
    yx += __shfl_xor(yx, m, 64);
    yy += __shfl_xor(yy, m, 64);
    mx = fmaxf(mx, __shfl_xor(mx, m, 64));
  }
  if (lane == 0) {
    fr[wave][0] = xx; fr[wave][1] = xy; fr[wave][2] = yx; fr[wave][3] = yy; fr[wave][4] = mx;
  }
  __syncthreads();
  if (tid == 0) {
    float sxx = 0, sxy = 0, syx = 0, syy = 0, smx = 0;
    for (int w = 0; w < 4; ++w) {
      sxx += fr[w][0]; sxy += fr[w][1]; syx += fr[w][2]; syy += fr[w][3];
      smx = fmaxf(smx, fr[w][4]);
    }
    const float inv = 1.0f / (4096.0f * 64.0f);  // /(64*64) then /P
    out[0] = (sxx + syy - sxy - syx) * inv;
    out[1] = smx;
    out[2] = sxx * inv;
    out[3] = syy * inv;
    out[4] = sxy * inv;
    out[5] = syx * inv;
  }
}

extern "C" void kernel_launch(void* const* d_in, const int* in_sizes, int n_in,
                              void* d_out, int out_size, void* d_ws, size_t ws_size,
                              hipStream_t stream) {
  const float* src = (const float*)d_in[0];
  const float* tgt = (const float*)d_in[1];
  float* out = (float*)d_out;
  float* ws = (float*)d_ws;  // slabs 16.8 MB + 256 gsum + 256 float4 partials
  gram_kernel<<<NBLK, 1024, 0, stream>>>(src, tgt, ws);
  reduce_kernel<<<NBLK, 1024, 0, stream>>>(ws, out);
  final_kernel<<<1, 256, 0, stream>>>(ws, out);
}